// Round 3
// baseline (331.417 us; speedup 1.0000x reference)
//
#include <hip/hip_runtime.h>
#include <hip/hip_cooperative_groups.h>

// Problem constants (fixed by the reference file)
constexpr int B_ = 4;
constexpr int M_ = 8192;          // nodes per graph
constexpr int N_ = B_ * M_;       // 32768
constexpr int K_ = 16;            // START_K, K_INCREMENT = 0
constexpr int NX_ = N_ * 64;      // 2097152
constexpr int G_ = 16;            // grid cells per axis
constexpr int C_ = G_ * G_;       // 256 cells/graph
constexpr int CT_ = B_ * C_;      // 1024 cells total
constexpr float CW_ = 62.5f;      // cell width (exact)
constexpr float INVW_ = 0.016f;   // binning scale (slop covered by ring eps)
constexpr int MAXSTAGE = 512;     // 3x3 staging capacity (lambda=288, 13 sigma)

// Flat f32 output layout (outputs concatenated in return order)
constexpr long long OFF_X      = 0;
constexpr long long OFF_POS    = OFF_X + NX_;
constexpr long long OFF_EI_SRC = OFF_POS + 2LL * N_;
constexpr long long OFF_EI_TGT = OFF_EI_SRC + 1LL * N_ * K_;
constexpr long long OFF_W      = OFF_EI_TGT + 1LL * N_ * K_;
constexpr long long OFF_BATCH  = OFF_W + 1LL * N_ * K_;
constexpr long long OFF_PERM   = OFF_BATCH + N_;
constexpr long long OFF_SCORE  = OFF_PERM + N_;

// Workspace layout (bytes)
constexpr size_t WS_STARTS  = 0;                      // int[1024]
constexpr size_t WS_COUNTS  = 4096;                   // int[1024]
constexpr size_t WS_PTR     = 8192;                   // int[1024]
constexpr size_t WS_MAXBITS = 12288;                  // uint
constexpr size_t WS_CELLID  = 16384;                  // int[N]
constexpr size_t WS_POSP    = WS_CELLID + 4ull * N_;  // float2[N]
constexpr size_t WS_BPOS    = WS_POSP + 8ull * N_;    // float2[N]
constexpr size_t WS_BLIDX   = WS_BPOS + 8ull * N_;    // int[N]
constexpr size_t WS_BQ      = WS_BLIDX + 4ull * N_;   // int[N]

// 16-deep ascending-sorted u64 list insert (branchless bubble).
#define INSERT16(L, keyv)                                   \
  {                                                         \
    unsigned long long _k = (keyv);                         \
    _Pragma("unroll")                                       \
    for (int _t = 0; _t < K_; ++_t) {                       \
      const unsigned long long _a = (L)[_t];                \
      const bool _lt = _k < _a;                             \
      (L)[_t] = _lt ? _k : _a;                              \
      _k = _lt ? _a : _k;                                   \
    }                                                       \
  }

// ---------------------------------------------------------------------------
// K1: pass-through copies + pos gather + tgt row + cellid. 524288 threads.
// ---------------------------------------------------------------------------
__global__ __launch_bounds__(256) void misc_count_kernel(
    const float* __restrict__ x, const float* __restrict__ pos,
    const int* __restrict__ batch, const int* __restrict__ perm,
    const float* __restrict__ score, float* __restrict__ out,
    float2* __restrict__ pos_pw, int* __restrict__ cellid,
    unsigned int* __restrict__ maxbits) {
  const int i = blockIdx.x * 256 + threadIdx.x;
  reinterpret_cast<float4*>(out + OFF_X)[i] =
      reinterpret_cast<const float4*>(x)[i];
  out[OFF_EI_TGT + i] = (float)(i >> 4);   // tgt = repeat(arange(N), 16)
  if (i < N_) {
    const int p = perm[i];
    const float px = pos[2 * p], py = pos[2 * p + 1];
    pos_pw[i] = make_float2(px, py);
    out[OFF_POS + 2 * i]     = px;
    out[OFF_POS + 2 * i + 1] = py;
    out[OFF_BATCH + i] = (float)batch[i];
    out[OFF_PERM + i]  = (float)p;
    out[OFF_SCORE + i] = score[i];
    int cx = (int)(px * INVW_); cx = cx < 0 ? 0 : (cx > 15 ? 15 : cx);
    int cy = (int)(py * INVW_); cy = cy < 0 ? 0 : (cy > 15 ? 15 : cy);
    cellid[i] = (i >> 13) * C_ + (cy << 4) + cx;
    if (i == 0) *maxbits = 0u;
  }
}

// ---------------------------------------------------------------------------
// K2: single-block histogram + exclusive scan over the 1024 cells.
// ---------------------------------------------------------------------------
__global__ __launch_bounds__(1024) void hist_scan_kernel(
    const int* __restrict__ cellid, int* __restrict__ counts,
    int* __restrict__ starts, int* __restrict__ cellptr) {
  __shared__ int h[CT_];
  const int t = threadIdx.x;
  h[t] = 0;
  __syncthreads();
  for (int i = t; i < N_; i += 1024) atomicAdd(&h[cellid[i]], 1);
  __syncthreads();
  const int c = h[t];
  __syncthreads();
  for (int off = 1; off < CT_; off <<= 1) {
    const int add = (t >= off) ? h[t - off] : 0;
    __syncthreads();
    h[t] += add;
    __syncthreads();
  }
  const int excl = h[t] - c;
  counts[t] = c;
  starts[t] = excl;
  cellptr[t] = excl;
}

// ---------------------------------------------------------------------------
// K3: scatter nodes into binned arrays (order-free thanks to (d2,idx) keys).
// ---------------------------------------------------------------------------
__global__ __launch_bounds__(256) void scatter_kernel(
    const float2* __restrict__ pos_pw, const int* __restrict__ cellid,
    int* __restrict__ cellptr, float2* __restrict__ bpos,
    int* __restrict__ blidx, int* __restrict__ bq) {
  const int i = blockIdx.x * 256 + threadIdx.x;
  if (i >= N_) return;
  const int s = atomicAdd(&cellptr[cellid[i]], 1);
  bpos[s] = pos_pw[i];
  blidx[s] = i & (M_ - 1);
  bq[s] = i;
}

// ---------------------------------------------------------------------------
// K4 (cooperative): exact KNN. One block per cell; 3x3 neighborhood staged in
// LDS; 2 lanes per query scan interleaved halves; sorted lists merged with a
// register bitonic merge via shfl; rare ring>=2 expansion from global memory.
// After grid.sync(): in-place edge-weight normalization.
// ---------------------------------------------------------------------------
__global__ __launch_bounds__(64) void knn_cell_kernel(
    const int* __restrict__ starts, const int* __restrict__ counts,
    const float2* __restrict__ bpos, const int* __restrict__ blidx,
    const int* __restrict__ bq, float* __restrict__ out,
    unsigned int* __restrict__ maxbits) {
  __shared__ float2 s_pos[MAXSTAGE];
  __shared__ int    s_li[MAXSTAGE];
  __shared__ int    s_s0[9], s_cnt[9], s_off[9];
  __shared__ int    s_g0[9], s_gn[9];
  __shared__ int    s_meta[3];  // ncells-staged info: tot, ngc (set by t0)

  const int t = threadIdx.x;
  const int cell = blockIdx.x;
  const int g = cell >> 8;
  const int lcell = cell & 255;
  const int qcx = lcell & 15, qcy = lcell >> 4;
  const int cellbase = g << 8;

  // ---- stage 3x3 clamped neighborhood ----
  const int nx0 = qcx > 0 ? qcx - 1 : 0, nx1 = qcx < 15 ? qcx + 1 : 15;
  const int ny0 = qcy > 0 ? qcy - 1 : 0, ny1 = qcy < 15 ? qcy + 1 : 15;
  const int nw = nx1 - nx0 + 1;
  const int ncells = nw * (ny1 - ny0 + 1);
  if (t < ncells) {
    const int yy = ny0 + t / nw, xx = nx0 + t % nw;
    const int c = cellbase + (yy << 4) + xx;
    s_s0[t] = starts[c];
    s_cnt[t] = counts[c];
  }
  __syncthreads();
  if (t == 0) {
    int tot = 0, ngc = 0;
    for (int r = 0; r < ncells; ++r) {
      if (tot + s_cnt[r] <= MAXSTAGE) { s_off[r] = tot; tot += s_cnt[r]; }
      else { s_off[r] = -1; s_g0[ngc] = s_s0[r]; s_gn[ngc] = s_cnt[r]; ++ngc; }
    }
    s_meta[0] = tot; s_meta[1] = ngc;
  }
  __syncthreads();
  for (int r = 0; r < ncells; ++r) {
    const int off = s_off[r];
    if (off >= 0) {
      const int cnt = s_cnt[r], s0 = s_s0[r];
      for (int j = t; j < cnt; j += 64) {
        s_pos[off + j] = bpos[s0 + j];
        s_li[off + j] = blidx[s0 + j];
      }
    }
  }
  __syncthreads();

  const int tot = s_meta[0], ngc = s_meta[1];
  const int qstart = starts[cell], qn = counts[cell];
  const int pair = t >> 1, l = t & 1;
  float mx = 0.f;

  for (int qi = pair; qi < qn; qi += 32) {
    const int slot = qstart + qi;
    const float2 qp = bpos[slot];
    const float qx = qp.x, qy = qp.y;

    unsigned long long lst[K_];
#pragma unroll
    for (int s = 0; s < K_; ++s) lst[s] = ~0ull;

    // interleaved scan of staged candidates (lane l takes j = l, l+2, ...)
    for (int j = l; j < tot; j += 2) {
      const float2 cp = s_pos[j];
      const float dx = __fsub_rn(cp.x, qx), dy = __fsub_rn(cp.y, qy);
      const float d2 = __fadd_rn(__fmul_rn(dx, dx), __fmul_rn(dy, dy));
      const unsigned db = __float_as_uint(d2);
      if (db <= (unsigned)(lst[K_ - 1] >> 32)) {
        const unsigned long long key =
            ((unsigned long long)db << 32) | (unsigned)s_li[j];
        if (key < lst[K_ - 1]) INSERT16(lst, key);
      }
    }
    // overflow cells (staging full — never for this data, kept for correctness)
    for (int r = 0; r < ngc; ++r) {
      const int s0 = s_g0[r], e0 = s0 + s_gn[r];
      for (int j = s0 + l; j < e0; j += 2) {
        const float2 bp = bpos[j];
        const float dx = __fsub_rn(bp.x, qx), dy = __fsub_rn(bp.y, qy);
        const float d2 = __fadd_rn(__fmul_rn(dx, dx), __fmul_rn(dy, dy));
        const unsigned db = __float_as_uint(d2);
        if (db <= (unsigned)(lst[K_ - 1] >> 32)) {
          const unsigned long long key =
              ((unsigned long long)db << 32) | (unsigned)blidx[j];
          if (key < lst[K_ - 1]) INSERT16(lst, key);
        }
      }
    }

    // ---- merge the pair's two sorted 16-lists: top-16 of union ----
    unsigned long long mrg[K_];
#pragma unroll
    for (int s = 0; s < K_; ++s) {
      const unsigned long long pv = __shfl_xor(lst[K_ - 1 - s], 1, 64);
      mrg[s] = lst[s] < pv ? lst[s] : pv;  // half-cleaner: bitonic lower half
    }
#pragma unroll
    for (int k = 8; k; k >>= 1) {
#pragma unroll
      for (int i = 0; i < K_; ++i) {
        if ((i & k) == 0) {
          const int j2 = i | k;
          const unsigned long long a = mrg[i], b = mrg[j2];
          mrg[i] = a < b ? a : b;
          mrg[j2] = a < b ? b : a;
        }
      }
    }

    if (l == 0) {
      // ---- rare ring >= 2 expansion from global (exactness guard) ----
      for (int c = 2; c <= 15; ++c) {
        if (mrg[K_ - 1] != ~0ull) {
          const float bnd = (float)(c - 1) * CW_ - 0.01f;
          const float kth = __uint_as_float((unsigned)(mrg[K_ - 1] >> 32));
          if (bnd * bnd > kth) break;
        }
        const int x0 = qcx - c, x1 = qcx + c, y0 = qcy - c, y1 = qcy + c;
        const int xs = x0 < 0 ? 0 : x0, xe = x1 > 15 ? 15 : x1;
        const int ys = y0 < 0 ? 0 : y0, ye = y1 > 15 ? 15 : y1;
        for (int y = ys; y <= ye; ++y) {
          const bool fullrow = (y == y0 || y == y1);
          for (int xx = xs; xx <= xe; ++xx) {
            if (!fullrow && xx != x0 && xx != x1) continue;
            const int cc = cellbase + (y << 4) + xx;
            const int s0 = starts[cc], e0 = s0 + counts[cc];
            for (int j = s0; j < e0; ++j) {
              const float2 bp = bpos[j];
              const float dx = __fsub_rn(bp.x, qx), dy = __fsub_rn(bp.y, qy);
              const float d2 = __fadd_rn(__fmul_rn(dx, dx), __fmul_rn(dy, dy));
              const unsigned db = __float_as_uint(d2);
              if (db <= (unsigned)(mrg[K_ - 1] >> 32)) {
                const unsigned long long key =
                    ((unsigned long long)db << 32) | (unsigned)blidx[j];
                if (key < mrg[K_ - 1]) INSERT16(mrg, key);
              }
            }
          }
        }
      }
      // ---- output (owner lane) ----
      const int gq = bq[slot];
      const int base = g << 13;
#pragma unroll
      for (int s = 0; s < K_; ++s) {
        const unsigned j = (unsigned)(mrg[s] & 0xffffffffu);
        const float d2 = __uint_as_float((unsigned)(mrg[s] >> 32));
        const float d = sqrtf(d2);
        out[OFF_EI_SRC + (long long)gq * K_ + s] = (float)(base + (int)j);
        out[OFF_W + (long long)gq * K_ + s] = d;
        mx = fmaxf(mx, d);
      }
    }
  }

  // ---- global max of distances ----
#pragma unroll
  for (int o = 32; o; o >>= 1) mx = fmaxf(mx, __shfl_xor(mx, o, 64));
  if (t == 0) atomicMax(maxbits, __float_as_uint(mx));

  // ---- grid-wide sync, then normalize weights in place ----
  cooperative_groups::this_grid().sync();
  const float m = __uint_as_float(*maxbits);
  const int tg = blockIdx.x * 64 + t;            // 65536 threads
  float4* w4 = reinterpret_cast<float4*>(out + OFF_W);
#pragma unroll
  for (int r = 0; r < 2; ++r) {
    const int idx = tg + r * 65536;              // 131072 float4s total
    float4 v = w4[idx];
    v.x /= m; v.y /= m; v.z /= m; v.w /= m;
    w4[idx] = v;
  }
}

extern "C" void kernel_launch(void* const* d_in, const int* in_sizes, int n_in,
                              void* d_out, int out_size, void* d_ws, size_t ws_size,
                              hipStream_t stream) {
  const float* x     = (const float*)d_in[0];
  const float* pos   = (const float*)d_in[1];
  const int*   batch = (const int*)d_in[4];
  const int*   perm  = (const int*)d_in[5];
  const float* score = (const float*)d_in[6];
  float* out = (float*)d_out;

  char* ws = (char*)d_ws;
  int*          startsA = (int*)(ws + WS_STARTS);
  int*          countsA = (int*)(ws + WS_COUNTS);
  int*          cellptr = (int*)(ws + WS_PTR);
  unsigned int* maxbits = (unsigned int*)(ws + WS_MAXBITS);
  int*          cellid  = (int*)(ws + WS_CELLID);
  float2*       pos_pw  = (float2*)(ws + WS_POSP);
  float2*       bpos    = (float2*)(ws + WS_BPOS);
  int*          blidx   = (int*)(ws + WS_BLIDX);
  int*          bq      = (int*)(ws + WS_BQ);

  hipLaunchKernelGGL(misc_count_kernel, dim3(NX_ / 4 / 256), dim3(256), 0,
                     stream, x, pos, batch, perm, score, out, pos_pw, cellid,
                     maxbits);
  hipLaunchKernelGGL(hist_scan_kernel, dim3(1), dim3(1024), 0, stream,
                     cellid, countsA, startsA, cellptr);
  hipLaunchKernelGGL(scatter_kernel, dim3(N_ / 256), dim3(256), 0, stream,
                     pos_pw, cellid, cellptr, bpos, blidx, bq);

  void* args[] = {(void*)&startsA, (void*)&countsA, (void*)&bpos,
                  (void*)&blidx, (void*)&bq, (void*)&out, (void*)&maxbits};
  hipLaunchCooperativeKernel((void*)knn_cell_kernel, dim3(CT_), dim3(64),
                             args, 0, stream);
}

// Round 4
// 184.908 us; speedup vs baseline: 1.7923x; 1.7923x over previous
//
#include <hip/hip_runtime.h>

// Problem constants (fixed by the reference file)
constexpr int B_ = 4;
constexpr int M_ = 8192;          // nodes per graph
constexpr int N_ = B_ * M_;       // 32768
constexpr int K_ = 16;            // START_K, K_INCREMENT = 0
constexpr int NX_ = N_ * 64;      // 2097152
constexpr int G_ = 16;            // grid cells per axis
constexpr int C_ = G_ * G_;       // 256 cells/graph
constexpr int CT_ = B_ * C_;      // 1024 cells total
constexpr float CW_ = 62.5f;      // cell width (exact)
constexpr float INVW_ = 0.016f;   // binning scale (slop covered by ring eps)
constexpr int CAP_ = 96;          // padded bin capacity (lambda=32, +11 sigma)
constexpr int STMAX_ = 9 * CAP_;  // 864 staged candidates max

// Flat f32 output layout (outputs concatenated in return order)
constexpr long long OFF_X      = 0;
constexpr long long OFF_POS    = OFF_X + NX_;
constexpr long long OFF_EI_SRC = OFF_POS + 2LL * N_;
constexpr long long OFF_EI_TGT = OFF_EI_SRC + 1LL * N_ * K_;
constexpr long long OFF_W      = OFF_EI_TGT + 1LL * N_ * K_;
constexpr long long OFF_BATCH  = OFF_W + 1LL * N_ * K_;
constexpr long long OFF_PERM   = OFF_BATCH + N_;
constexpr long long OFF_SCORE  = OFF_PERM + N_;

// Workspace layout (bytes)
constexpr size_t WS_COUNTS  = 0;                          // int[1024]
constexpr size_t WS_MAXBITS = 4096;                       // uint
constexpr size_t WS_BPOS    = 8192;                       // float2[CT_*CAP_]
constexpr size_t WS_BQ      = WS_BPOS + 8ull * CT_ * CAP_; // int[CT_*CAP_]

// 16-deep ascending-sorted u64 list insert (branchless bubble).
#define INSERT16(L, keyv)                                   \
  {                                                         \
    unsigned long long _k = (keyv);                         \
    _Pragma("unroll")                                       \
    for (int _t = 0; _t < K_; ++_t) {                       \
      const unsigned long long _a = (L)[_t];                \
      const bool _lt = _k < _a;                             \
      (L)[_t] = _lt ? _k : _a;                              \
      _k = _lt ? _a : _k;                                   \
    }                                                       \
  }

// Merge this lane's sorted-16 with partner (lane ^ STRIDE): keep union top-16.
// Half-cleaner (min vs reversed partner) -> bitonic merge network. R3-verified.
#define MERGE_ROUND(CUR, STRIDE)                                          \
  {                                                                       \
    unsigned long long _tmp[K_];                                          \
    _Pragma("unroll")                                                     \
    for (int _s = 0; _s < K_; ++_s) {                                     \
      const unsigned long long _pv = __shfl_xor((CUR)[K_ - 1 - _s], STRIDE, 64); \
      _tmp[_s] = (CUR)[_s] < _pv ? (CUR)[_s] : _pv;                       \
    }                                                                     \
    _Pragma("unroll")                                                     \
    for (int _k = 8; _k; _k >>= 1) {                                      \
      _Pragma("unroll")                                                   \
      for (int _i = 0; _i < K_; ++_i) {                                   \
        if ((_i & _k) == 0) {                                             \
          const unsigned long long _a = _tmp[_i], _b = _tmp[_i | _k];     \
          _tmp[_i] = _a < _b ? _a : _b;                                   \
          _tmp[_i | _k] = _a < _b ? _b : _a;                              \
        }                                                                 \
      }                                                                   \
    }                                                                     \
    _Pragma("unroll")                                                     \
    for (int _s = 0; _s < K_; ++_s) (CUR)[_s] = _tmp[_s];                 \
  }

// ---------------------------------------------------------------------------
// K1: pass-throughs + pos gather + tgt row + padded-bin scatter. 524288 thr.
// ---------------------------------------------------------------------------
__global__ __launch_bounds__(256) void prep_kernel(
    const float* __restrict__ x, const float* __restrict__ pos,
    const int* __restrict__ batch, const int* __restrict__ perm,
    const float* __restrict__ score, float* __restrict__ out,
    float2* __restrict__ bpos, int* __restrict__ bq,
    int* __restrict__ counts) {
  const int i = blockIdx.x * 256 + threadIdx.x;
  reinterpret_cast<float4*>(out + OFF_X)[i] =
      reinterpret_cast<const float4*>(x)[i];
  out[OFF_EI_TGT + i] = (float)(i >> 4);  // tgt = repeat(arange(N),16); N*K thr
  if (i < N_) {
    const int p = perm[i];
    const float px = pos[2 * p], py = pos[2 * p + 1];
    out[OFF_POS + 2 * i]     = px;
    out[OFF_POS + 2 * i + 1] = py;
    out[OFF_BATCH + i] = (float)batch[i];
    out[OFF_PERM + i]  = (float)p;
    out[OFF_SCORE + i] = score[i];
    int cx = (int)(px * INVW_); cx = cx < 0 ? 0 : (cx > 15 ? 15 : cx);
    int cy = (int)(py * INVW_); cy = cy < 0 ? 0 : (cy > 15 ? 15 : cy);
    const int cell = (i >> 13) * C_ + (cy << 4) + cx;
    const int r = atomicAdd(&counts[cell], 1);
    if (r < CAP_) {  // never overflows for this data; guarded for safety
      bpos[cell * CAP_ + r] = make_float2(px, py);
      bq[cell * CAP_ + r] = i;
    }
  }
}

// ---------------------------------------------------------------------------
// K2: exact KNN. One 256-thread block per cell, 8 lanes per query.
// 3x3 neighborhood staged in LDS; per-lane u64 top-16 over a 1/8 slice;
// 3 shfl-bitonic merge rounds; lane 0 does rare ring>=2 fallback + output.
// ---------------------------------------------------------------------------
__global__ __launch_bounds__(256) void knn_kernel(
    const int* __restrict__ counts, const float2* __restrict__ bpos,
    const int* __restrict__ bq, float* __restrict__ out,
    unsigned int* __restrict__ maxbits) {
  __shared__ float2 s_pos[STMAX_];
  __shared__ int    s_li[STMAX_];
  __shared__ int    s_c0[9], s_cnt[9], s_off[9];
  __shared__ int    s_tot;

  const int t = threadIdx.x;
  const int cell = blockIdx.x;
  const int qn = min(counts[cell], CAP_);
  if (qn == 0) return;  // uniform across block (before any __syncthreads)

  const int g = cell >> 8;
  const int lc = cell & 255;
  const int qcx = lc & 15, qcy = lc >> 4;
  const int cb = g << 8;

  const int nx0 = qcx > 0 ? qcx - 1 : 0, nx1 = qcx < 15 ? qcx + 1 : 15;
  const int ny0 = qcy > 0 ? qcy - 1 : 0, ny1 = qcy < 15 ? qcy + 1 : 15;
  const int nw = nx1 - nx0 + 1;
  const int ncl = nw * (ny1 - ny0 + 1);
  if (t < ncl) {
    const int c = cb + ((ny0 + t / nw) << 4) + (nx0 + t % nw);
    s_c0[t] = c * CAP_;
    s_cnt[t] = min(counts[c], CAP_);
  }
  __syncthreads();
  if (t == 0) {
    int tot = 0;
    for (int r = 0; r < ncl; ++r) { s_off[r] = tot; tot += s_cnt[r]; }
    s_tot = tot;
  }
  __syncthreads();
  for (int r = 0; r < ncl; ++r) {
    const int o = s_off[r], n = s_cnt[r], c0 = s_c0[r];
    for (int j = t; j < n; j += 256) {
      s_pos[o + j] = bpos[c0 + j];
      s_li[o + j] = bq[c0 + j] & (M_ - 1);
    }
  }
  __syncthreads();

  const int tot = s_tot;
  const int rq = (qcy - ny0) * nw + (qcx - nx0);   // query cell's staged slab
  const int qoff = s_off[rq];
  const int qbase = cell * CAP_;
  const int grp = t >> 3, ln = t & 7;
  float mx = 0.f;

  for (int qi = grp; qi < qn; qi += 32) {
    const float2 qp = s_pos[qoff + qi];
    const float qx = qp.x, qy = qp.y;

    unsigned long long lst[K_];
#pragma unroll
    for (int s = 0; s < K_; ++s) lst[s] = ~0ull;

    // per-lane 1/8 slice of staged candidates, unrolled x2 to pipeline LDS
    int j = ln;
    for (; j + 8 < tot; j += 16) {
      const float2 c0 = s_pos[j];
      const float2 c1 = s_pos[j + 8];
      const int li0 = s_li[j], li1 = s_li[j + 8];
      const float dx0 = __fsub_rn(c0.x, qx), dy0 = __fsub_rn(c0.y, qy);
      const float d20 = __fadd_rn(__fmul_rn(dx0, dx0), __fmul_rn(dy0, dy0));
      const float dx1 = __fsub_rn(c1.x, qx), dy1 = __fsub_rn(c1.y, qy);
      const float d21 = __fadd_rn(__fmul_rn(dx1, dx1), __fmul_rn(dy1, dy1));
      const unsigned long long k0 =
          ((unsigned long long)__float_as_uint(d20) << 32) | (unsigned)li0;
      const unsigned long long k1 =
          ((unsigned long long)__float_as_uint(d21) << 32) | (unsigned)li1;
      if (k0 < lst[K_ - 1]) INSERT16(lst, k0);
      if (k1 < lst[K_ - 1]) INSERT16(lst, k1);
    }
    for (; j < tot; j += 8) {
      const float2 c0 = s_pos[j];
      const float dx = __fsub_rn(c0.x, qx), dy = __fsub_rn(c0.y, qy);
      const float d2 = __fadd_rn(__fmul_rn(dx, dx), __fmul_rn(dy, dy));
      const unsigned long long k0 =
          ((unsigned long long)__float_as_uint(d2) << 32) | (unsigned)s_li[j];
      if (k0 < lst[K_ - 1]) INSERT16(lst, k0);
    }

    // merge the 8 lanes' lists -> all 8 hold union top-16
    MERGE_ROUND(lst, 1)
    MERGE_ROUND(lst, 2)
    MERGE_ROUND(lst, 4)

    if (ln == 0) {
      // rare ring >= 2 fallback from global (exactness guard)
      for (int c = 2; c <= 15; ++c) {
        if (lst[K_ - 1] != ~0ull) {
          const float bnd = (float)(c - 1) * CW_ - 0.01f;
          const float kth = __uint_as_float((unsigned)(lst[K_ - 1] >> 32));
          if (bnd * bnd > kth) break;
        }
        const int x0 = qcx - c, x1 = qcx + c, y0 = qcy - c, y1 = qcy + c;
        const int xs = x0 < 0 ? 0 : x0, xe = x1 > 15 ? 15 : x1;
        const int ys = y0 < 0 ? 0 : y0, ye = y1 > 15 ? 15 : y1;
        for (int y = ys; y <= ye; ++y) {
          const bool fullrow = (y == y0 || y == y1);
          for (int xx = xs; xx <= xe; ++xx) {
            if (!fullrow && xx != x0 && xx != x1) continue;
            const int cc = cb + (y << 4) + xx;
            const int s0 = cc * CAP_, e0 = s0 + min(counts[cc], CAP_);
            for (int jj = s0; jj < e0; ++jj) {
              const float2 bp = bpos[jj];
              const float dx = __fsub_rn(bp.x, qx), dy = __fsub_rn(bp.y, qy);
              const float d2 = __fadd_rn(__fmul_rn(dx, dx), __fmul_rn(dy, dy));
              const unsigned long long key =
                  ((unsigned long long)__float_as_uint(d2) << 32) |
                  (unsigned)(bq[jj] & (M_ - 1));
              if (key < lst[K_ - 1]) INSERT16(lst, key);
            }
          }
        }
      }
      // output
      const int gq = bq[qbase + qi];
      const int base = g << 13;
#pragma unroll
      for (int s = 0; s < K_; ++s) {
        const unsigned jn = (unsigned)(lst[s] & 0xffffffffu);
        const float d2 = __uint_as_float((unsigned)(lst[s] >> 32));
        const float d = sqrtf(d2);
        out[OFF_EI_SRC + (long long)gq * K_ + s] = (float)(base + (int)jn);
        out[OFF_W + (long long)gq * K_ + s] = d;
        mx = fmaxf(mx, d);
      }
    }
  }

  // global max of distances (f32 bits monotone for >= 0)
#pragma unroll
  for (int o = 32; o; o >>= 1) mx = fmaxf(mx, __shfl_xor(mx, o, 64));
  if ((t & 63) == 0) atomicMax(maxbits, __float_as_uint(mx));
}

// ---------------------------------------------------------------------------
// K3: weight[i] = dist[i] / max(dist). 131072 float4s.
// ---------------------------------------------------------------------------
__global__ __launch_bounds__(256) void norm_kernel(
    float* __restrict__ out, const unsigned int* __restrict__ maxbits) {
  const float m = __uint_as_float(*maxbits);
  const int i = blockIdx.x * 256 + threadIdx.x;
  float4* w4 = reinterpret_cast<float4*>(out + OFF_W);
  float4 v = w4[i];
  v.x /= m; v.y /= m; v.z /= m; v.w /= m;
  w4[i] = v;
}

extern "C" void kernel_launch(void* const* d_in, const int* in_sizes, int n_in,
                              void* d_out, int out_size, void* d_ws, size_t ws_size,
                              hipStream_t stream) {
  const float* x     = (const float*)d_in[0];
  const float* pos   = (const float*)d_in[1];
  const int*   batch = (const int*)d_in[4];
  const int*   perm  = (const int*)d_in[5];
  const float* score = (const float*)d_in[6];
  float* out = (float*)d_out;

  char* ws = (char*)d_ws;
  int*          counts  = (int*)(ws + WS_COUNTS);
  unsigned int* maxbits = (unsigned int*)(ws + WS_MAXBITS);
  float2*       bpos    = (float2*)(ws + WS_BPOS);
  int*          bq      = (int*)(ws + WS_BQ);

  hipMemsetAsync(ws, 0, WS_MAXBITS + sizeof(unsigned int), stream);

  hipLaunchKernelGGL(prep_kernel, dim3(NX_ / 4 / 256), dim3(256), 0, stream,
                     x, pos, batch, perm, score, out, bpos, bq, counts);
  hipLaunchKernelGGL(knn_kernel, dim3(CT_), dim3(256), 0, stream,
                     counts, bpos, bq, out, maxbits);
  hipLaunchKernelGGL(norm_kernel, dim3(N_ * K_ / 4 / 256), dim3(256), 0,
                     stream, out, maxbits);
}

// Round 6
// 167.207 us; speedup vs baseline: 1.9821x; 1.1059x over previous
//
#include <hip/hip_runtime.h>
#include <cfloat>

// Problem constants (fixed by the reference file)
constexpr int B_ = 4;
constexpr int M_ = 8192;          // nodes per graph
constexpr int N_ = B_ * M_;       // 32768
constexpr int K_ = 16;            // START_K, K_INCREMENT = 0
constexpr int NX_ = N_ * 64;      // 2097152
constexpr int G_ = 16;            // grid cells per axis
constexpr int C_ = G_ * G_;       // 256 cells/graph
constexpr int CT_ = B_ * C_;      // 1024 cells total
constexpr float CW_ = 62.5f;      // cell width (exact)
constexpr float INVW_ = 0.016f;   // binning scale (slop covered by ring eps)
constexpr int CAP_ = 96;          // padded bin capacity (lambda=32, +11 sigma)
constexpr int STMAX_ = 9 * CAP_;  // 864 staged candidates max
constexpr int SCAP_ = 13;         // per-lane stack stride (u64; odd -> bank spread)
constexpr int SDEPTH_ = 12;       // usable stack depth

// Flat f32 output layout (outputs concatenated in return order)
constexpr long long OFF_X      = 0;
constexpr long long OFF_POS    = OFF_X + NX_;
constexpr long long OFF_EI_SRC = OFF_POS + 2LL * N_;
constexpr long long OFF_EI_TGT = OFF_EI_SRC + 1LL * N_ * K_;
constexpr long long OFF_W      = OFF_EI_TGT + 1LL * N_ * K_;
constexpr long long OFF_BATCH  = OFF_W + 1LL * N_ * K_;
constexpr long long OFF_PERM   = OFF_BATCH + N_;
constexpr long long OFF_SCORE  = OFF_PERM + N_;

// Workspace layout (bytes)
constexpr size_t WS_COUNTS  = 0;                           // int[1024]
constexpr size_t WS_MAXBITS = 4096;                        // uint
constexpr size_t WS_BPOS    = 8192;                        // float2[CT_*CAP_]
constexpr size_t WS_BQ      = WS_BPOS + 8ull * CT_ * CAP_; // int[CT_*CAP_]

// 16-deep ascending-sorted u64 list insert (branchless bubble).
#define INSERT16(L, keyv)                                   \
  {                                                         \
    unsigned long long _k = (keyv);                         \
    _Pragma("unroll")                                       \
    for (int _t = 0; _t < K_; ++_t) {                       \
      const unsigned long long _a = (L)[_t];                \
      const bool _lt = _k < _a;                             \
      (L)[_t] = _lt ? _k : _a;                              \
      _k = _lt ? _a : _k;                                   \
    }                                                       \
  }

// Merge this lane's sorted-16 with partner (lane ^ STRIDE): union top-16.
// Half-cleaner (min vs reversed partner) + bitonic clean. R3/R4-verified.
#define MERGE_ROUND(CUR, STRIDE)                                          \
  {                                                                       \
    unsigned long long _tmp[K_];                                          \
    _Pragma("unroll")                                                     \
    for (int _s = 0; _s < K_; ++_s) {                                     \
      const unsigned long long _pv = __shfl_xor((CUR)[K_ - 1 - _s], STRIDE, 64); \
      _tmp[_s] = (CUR)[_s] < _pv ? (CUR)[_s] : _pv;                       \
    }                                                                     \
    _Pragma("unroll")                                                     \
    for (int _k = 8; _k; _k >>= 1) {                                      \
      _Pragma("unroll")                                                   \
      for (int _i = 0; _i < K_; ++_i) {                                   \
        if ((_i & _k) == 0) {                                             \
          const unsigned long long _a = _tmp[_i], _b = _tmp[_i | _k];     \
          _tmp[_i] = _a < _b ? _a : _b;                                   \
          _tmp[_i | _k] = _a < _b ? _b : _a;                              \
        }                                                                 \
      }                                                                   \
    }                                                                     \
    _Pragma("unroll")                                                     \
    for (int _s = 0; _s < K_; ++_s) (CUR)[_s] = _tmp[_s];                 \
  }

#define D2(cpx, cpy)                                                      \
  __fadd_rn(__fmul_rn(__fsub_rn(cpx, qx), __fsub_rn(cpx, qx)),            \
            __fmul_rn(__fsub_rn(cpy, qy), __fsub_rn(cpy, qy)))

// ---------------------------------------------------------------------------
// K1: pass-throughs + pos gather + tgt row + padded-bin scatter. 524288 thr.
// (identical to R4 — proven)
// ---------------------------------------------------------------------------
__global__ __launch_bounds__(256) void prep_kernel(
    const float* __restrict__ x, const float* __restrict__ pos,
    const int* __restrict__ batch, const int* __restrict__ perm,
    const float* __restrict__ score, float* __restrict__ out,
    float2* __restrict__ bpos, int* __restrict__ bq,
    int* __restrict__ counts) {
  const int i = blockIdx.x * 256 + threadIdx.x;
  reinterpret_cast<float4*>(out + OFF_X)[i] =
      reinterpret_cast<const float4*>(x)[i];
  out[OFF_EI_TGT + i] = (float)(i >> 4);  // tgt = repeat(arange(N),16)
  if (i < N_) {
    const int p = perm[i];
    const float px = pos[2 * p], py = pos[2 * p + 1];
    out[OFF_POS + 2 * i]     = px;
    out[OFF_POS + 2 * i + 1] = py;
    out[OFF_BATCH + i] = (float)batch[i];
    out[OFF_PERM + i]  = (float)p;
    out[OFF_SCORE + i] = score[i];
    int cx = (int)(px * INVW_); cx = cx < 0 ? 0 : (cx > 15 ? 15 : cx);
    int cy = (int)(py * INVW_); cy = cy < 0 ? 0 : (cy > 15 ? 15 : cy);
    const int cell = (i >> 13) * C_ + (cy << 4) + cx;
    const int r = atomicAdd(&counts[cell], 1);
    if (r < CAP_) {  // never overflows for this data; guarded for safety
      bpos[cell * CAP_ + r] = make_float2(px, py);
      bq[cell * CAP_ + r] = i;
    }
  }
}

// ---------------------------------------------------------------------------
// K2: exact KNN. One 256-thread block per cell, 8 lanes per query.
// NEW vs R4: exact data-derived threshold tau (max-d2 of first 16 own-cell
// pts, refined by survivor counts at tau/{2,4,8}); survivors appended to
// per-lane LDS stacks (cheap under divergence), then dense drain + the
// R4-verified 3-round bitonic merge. Overflow / qn<16 -> R4 direct path.
// ---------------------------------------------------------------------------
__global__ __launch_bounds__(256) void knn_kernel(
    const int* __restrict__ counts, const float2* __restrict__ bpos,
    const int* __restrict__ bq, float* __restrict__ out,
    unsigned int* __restrict__ maxbits) {
  __shared__ float2 s_pos[STMAX_];
  __shared__ int    s_li[STMAX_];
  __shared__ unsigned long long s_stk[256 * SCAP_];
  __shared__ int    s_c0[9], s_cnt[9], s_off[9];
  __shared__ int    s_tot;

  const int t = threadIdx.x;
  const int cell = blockIdx.x;
  const int qn = min(counts[cell], CAP_);
  if (qn == 0) return;  // uniform across block (before any __syncthreads)

  const int g = cell >> 8;
  const int lc = cell & 255;
  const int qcx = lc & 15, qcy = lc >> 4;
  const int cb = g << 8;

  const int nx0 = qcx > 0 ? qcx - 1 : 0, nx1 = qcx < 15 ? qcx + 1 : 15;
  const int ny0 = qcy > 0 ? qcy - 1 : 0, ny1 = qcy < 15 ? qcy + 1 : 15;
  const int nw = nx1 - nx0 + 1;
  const int ncl = nw * (ny1 - ny0 + 1);
  if (t < ncl) {
    const int c = cb + ((ny0 + t / nw) << 4) + (nx0 + t % nw);
    s_c0[t] = c * CAP_;
    s_cnt[t] = min(counts[c], CAP_);
  }
  __syncthreads();
  if (t == 0) {
    int tot = 0;
    for (int r = 0; r < ncl; ++r) { s_off[r] = tot; tot += s_cnt[r]; }
    s_tot = tot;
  }
  __syncthreads();
  for (int r = 0; r < ncl; ++r) {
    const int o = s_off[r], n = s_cnt[r], c0 = s_c0[r];
    for (int j = t; j < n; j += 256) {
      s_pos[o + j] = bpos[c0 + j];
      s_li[o + j] = bq[c0 + j] & (M_ - 1);
    }
  }
  __syncthreads();

  const int tot = s_tot;
  const int rq = (qcy - ny0) * nw + (qcx - nx0);   // query cell's staged slab
  const int qoff = s_off[rq];
  const int qbase = cell * CAP_;
  const int grp = t >> 3, ln = t & 7;
  unsigned long long* stk = &s_stk[t * SCAP_];
  float mx = 0.f;

  for (int qi = grp; qi < qn; qi += 32) {
    const float2 qp = s_pos[qoff + qi];
    const float qx = qp.x, qy = qp.y;

    // --- exact threshold: max d2 over first 16 own-cell points ---
    float md = 0.f;
#pragma unroll
    for (int m = ln; m < 16; m += 8) {  // 2 probes/lane
      const int mm = m < qn ? m : 0;    // keep LDS read in the staged slab
      const float2 cp = s_pos[qoff + mm];
      const float d2p = D2(cp.x, cp.y);
      if (m < qn) md = fmaxf(md, d2p);
    }
    md = fmaxf(md, __shfl_xor(md, 1, 64));
    md = fmaxf(md, __shfl_xor(md, 2, 64));
    md = fmaxf(md, __shfl_xor(md, 4, 64));
    const float t0 = (qn >= K_) ? md : FLT_MAX;
    const float t1 = t0 * 0.5f, t2 = t0 * 0.25f, t3 = t0 * 0.125f;

    // --- count survivors at refined thresholds (dense, no inserts) ---
    int pk = 0;  // c1 | c2<<10 | c3<<20  (each <= 864 < 1024)
    for (int j = ln; j < tot; j += 8) {
      const float2 cp = s_pos[j];
      const float d2 = D2(cp.x, cp.y);
      pk += (int)(d2 <= t1) + ((int)(d2 <= t2) << 10) + ((int)(d2 <= t3) << 20);
    }
    pk += __shfl_xor(pk, 1, 64);
    pk += __shfl_xor(pk, 2, 64);
    pk += __shfl_xor(pk, 4, 64);
    const int c1 = pk & 1023, c2 = (pk >> 10) & 1023, c3 = pk >> 20;
    const float tau = (c3 >= K_) ? t3 : (c2 >= K_) ? t2 : (c1 >= K_) ? t1 : t0;

    // --- append survivors to per-lane LDS stack (3-instr divergent body) ---
    int sp = 0, ovf = 0;
    for (int j = ln; j < tot; j += 8) {
      const float2 cp = s_pos[j];
      const float d2 = D2(cp.x, cp.y);
      if (d2 <= tau) {
        if (sp < SDEPTH_)
          stk[sp++] = ((unsigned long long)__float_as_uint(d2) << 32) |
                      (unsigned)s_li[j];
        else
          ovf = 1;
      }
    }
    ovf |= __shfl_xor(ovf, 1, 64);
    ovf |= __shfl_xor(ovf, 2, 64);
    ovf |= __shfl_xor(ovf, 4, 64);

    unsigned long long lst[K_];
#pragma unroll
    for (int s = 0; s < K_; ++s) lst[s] = ~0ull;

    if (!ovf) {
      // dense drain: all 256 lanes insert concurrently
      for (int m = 0; m < sp; ++m) {
        const unsigned long long k2 = stk[m];
        if (k2 < lst[K_ - 1]) INSERT16(lst, k2);
      }
    } else {
      // exact fallback = R4's proven direct gated scan of the 1/8 slice
      for (int j = ln; j < tot; j += 8) {
        const float2 cp = s_pos[j];
        const float d2 = D2(cp.x, cp.y);
        const unsigned db = __float_as_uint(d2);
        if (db <= (unsigned)(lst[K_ - 1] >> 32)) {
          const unsigned long long key =
              ((unsigned long long)db << 32) | (unsigned)s_li[j];
          if (key < lst[K_ - 1]) INSERT16(lst, key);
        }
      }
    }

    // merge the 8 lanes' lists -> all 8 hold union top-16
    MERGE_ROUND(lst, 1)
    MERGE_ROUND(lst, 2)
    MERGE_ROUND(lst, 4)

    if (ln == 0) {
      // rare ring >= 2 expansion from global bins (exactness guard)
      for (int c = 2; c <= 15; ++c) {
        if (lst[K_ - 1] != ~0ull) {
          const float bnd = (float)(c - 1) * CW_ - 0.01f;
          const float kth = __uint_as_float((unsigned)(lst[K_ - 1] >> 32));
          if (bnd * bnd > kth) break;
        }
        const int x0 = qcx - c, x1 = qcx + c, y0 = qcy - c, y1 = qcy + c;
        const int xs = x0 < 0 ? 0 : x0, xe = x1 > 15 ? 15 : x1;
        const int ys = y0 < 0 ? 0 : y0, ye = y1 > 15 ? 15 : y1;
        for (int y = ys; y <= ye; ++y) {
          const bool fullrow = (y == y0 || y == y1);
          for (int xx = xs; xx <= xe; ++xx) {
            if (!fullrow && xx != x0 && xx != x1) continue;
            const int cc = cb + (y << 4) + xx;
            const int s0 = cc * CAP_, e0 = s0 + min(counts[cc], CAP_);
            for (int jj = s0; jj < e0; ++jj) {
              const float2 bp = bpos[jj];
              const float d2 = D2(bp.x, bp.y);
              const unsigned db = __float_as_uint(d2);
              if (db <= (unsigned)(lst[K_ - 1] >> 32)) {
                const unsigned long long key =
                    ((unsigned long long)db << 32) |
                    (unsigned)(bq[jj] & (M_ - 1));
                if (key < lst[K_ - 1]) INSERT16(lst, key);
              }
            }
          }
        }
      }
      // output
      const int gq = bq[qbase + qi];
      const int base = g << 13;
#pragma unroll
      for (int s = 0; s < K_; ++s) {
        const unsigned jn = (unsigned)(lst[s] & 0xffffffffu);
        const float d2 = __uint_as_float((unsigned)(lst[s] >> 32));
        const float d = sqrtf(d2);
        out[OFF_EI_SRC + (long long)gq * K_ + s] = (float)(base + (int)jn);
        out[OFF_W + (long long)gq * K_ + s] = d;
        mx = fmaxf(mx, d);
      }
    }
  }

  // global max of distances (f32 bits monotone for >= 0)
#pragma unroll
  for (int o = 32; o; o >>= 1) mx = fmaxf(mx, __shfl_xor(mx, o, 64));
  if ((t & 63) == 0) atomicMax(maxbits, __float_as_uint(mx));
}

// ---------------------------------------------------------------------------
// K3: weight[i] = dist[i] / max(dist). 131072 float4s. (identical to R4)
// ---------------------------------------------------------------------------
__global__ __launch_bounds__(256) void norm_kernel(
    float* __restrict__ out, const unsigned int* __restrict__ maxbits) {
  const float m = __uint_as_float(*maxbits);
  const int i = blockIdx.x * 256 + threadIdx.x;
  float4* w4 = reinterpret_cast<float4*>(out + OFF_W);
  float4 v = w4[i];
  v.x /= m; v.y /= m; v.z /= m; v.w /= m;
  w4[i] = v;
}

extern "C" void kernel_launch(void* const* d_in, const int* in_sizes, int n_in,
                              void* d_out, int out_size, void* d_ws, size_t ws_size,
                              hipStream_t stream) {
  const float* x     = (const float*)d_in[0];
  const float* pos   = (const float*)d_in[1];
  const int*   batch = (const int*)d_in[4];
  const int*   perm  = (const int*)d_in[5];
  const float* score = (const float*)d_in[6];
  float* out = (float*)d_out;

  char* ws = (char*)d_ws;
  int*          counts  = (int*)(ws + WS_COUNTS);
  unsigned int* maxbits = (unsigned int*)(ws + WS_MAXBITS);
  float2*       bpos    = (float2*)(ws + WS_BPOS);
  int*          bq      = (int*)(ws + WS_BQ);

  hipMemsetAsync(ws, 0, WS_MAXBITS + sizeof(unsigned int), stream);

  hipLaunchKernelGGL(prep_kernel, dim3(NX_ / 4 / 256), dim3(256), 0, stream,
                     x, pos, batch, perm, score, out, bpos, bq, counts);
  hipLaunchKernelGGL(knn_kernel, dim3(CT_), dim3(256), 0, stream,
                     counts, bpos, bq, out, maxbits);
  hipLaunchKernelGGL(norm_kernel, dim3(N_ * K_ / 4 / 256), dim3(256), 0,
                     stream, out, maxbits);
}